// Round 11
// baseline (889.238 us; speedup 1.0000x reference)
//
#include <hip/hip_runtime.h>
#include <hip/hip_bf16.h>
#include <stdint.h>

#define TTOK 2048
#define DDIM 2048
#define IDIM 5632
#define NEXP 8

typedef __attribute__((ext_vector_type(8))) short bf16x8;
typedef __attribute__((ext_vector_type(4))) float f32x4;
typedef __attribute__((ext_vector_type(8))) unsigned short u16x8;
typedef __attribute__((ext_vector_type(4))) unsigned short u16x4;

__device__ __forceinline__ unsigned short f2bf(float f) {
  union { float f; uint32_t u; } v; v.f = f;
  uint32_t u = v.u + 0x7fffu + ((v.u >> 16) & 1u);
  return (unsigned short)(u >> 16);
}

__device__ __forceinline__ uint32_t fbits(float f) {
  union { float f; uint32_t u; } v; v.f = f; return v.u;
}

// truncating packed f32x2 -> bf16x2 via v_perm_b32 (1 inst per 2 values)
__device__ __forceinline__ u16x8 cvt8t(float4 a, float4 b) {
  union { u16x8 v; uint32_t w[4]; } r;
  r.w[0] = __builtin_amdgcn_perm(fbits(a.y), fbits(a.x), 0x07060302);
  r.w[1] = __builtin_amdgcn_perm(fbits(a.w), fbits(a.z), 0x07060302);
  r.w[2] = __builtin_amdgcn_perm(fbits(b.y), fbits(b.x), 0x07060302);
  r.w[3] = __builtin_amdgcn_perm(fbits(b.w), fbits(b.z), 0x07060302);
  return r.v;
}

typedef __attribute__((address_space(3))) void lds_t;
typedef const __attribute__((address_space(1))) void gbl_t;
__device__ __forceinline__ void gload16(const void* g, void* l) {
  __builtin_amdgcn_global_load_lds((gbl_t*)g, (lds_t*)l, 16, 0, 0);
}

// B half-tile ds_write (swizzled): thread writes its 16 fp32 as 2x u16x8
#define WRITE_B(buf, hh, r0, r1, r2, r3) do {                                  \
    *(u16x8*)&SB[buf][(hh)*128 + brow][((bcb + 0) ^ bswz) * 8] = cvt8t(r0, r1);\
    *(u16x8*)&SB[buf][(hh)*128 + brow][((bcb + 1) ^ bswz) * 8] = cvt8t(r2, r3);\
  } while (0)

// one 8-phase-template phase: frag ds-reads + stage + barriers + 16 MFMA
#define PHASE(buf, kk, mh, VM8, ...) do {                                      \
    const int cs_ = (((kk) * 4 + kc) ^ rsw) * 8;                               \
    bf16x8 afr[4];                                                             \
    _Pragma("unroll")                                                          \
    for (int m_ = 0; m_ < 4; ++m_)                                             \
      afr[m_] = *(const bf16x8*)&SA[buf][wr*128 + ((mh)*4 + m_)*16 + fr][cs_]; \
    if ((mh) == 0) {                                                           \
      _Pragma("unroll")                                                        \
      for (int n_ = 0; n_ < 4; ++n_)                                           \
        bfr[n_] = *(const bf16x8*)&SB[buf][wc*64 + n_*16 + fr][cs_];           \
    }                                                                          \
    __VA_ARGS__;                                                               \
    if (VM8) { asm volatile("s_waitcnt vmcnt(8)" ::: "memory"); }              \
    __builtin_amdgcn_s_barrier();                                              \
    asm volatile("s_waitcnt lgkmcnt(0)" ::: "memory");                         \
    __builtin_amdgcn_sched_barrier(0);                                         \
    __builtin_amdgcn_s_setprio(1);                                             \
    _Pragma("unroll")                                                          \
    for (int m_ = 0; m_ < 4; ++m_)                                             \
      _Pragma("unroll")                                                        \
      for (int n_ = 0; n_ < 4; ++n_)                                           \
        acc[(mh)*4 + m_][n_] = __builtin_amdgcn_mfma_f32_16x16x32_bf16(        \
            afr[m_], bfr[n_], acc[(mh)*4 + m_][n_], 0, 0, 0);                  \
    __builtin_amdgcn_s_setprio(0);                                             \
    __builtin_amdgcn_s_barrier();                                              \
  } while (0)

// ---------------- router: logits, top-2, softmax, expert lists, x->bf16 ----------------
__global__ __launch_bounds__(256) void router_kernel(
    const float* __restrict__ x, const float* __restrict__ gw,
    unsigned short* __restrict__ xbf,
    int* __restrict__ cnt, int* __restrict__ slots, float* __restrict__ wts)
{
  const int lane = threadIdx.x & 63;
  const int t = (blockIdx.x * blockDim.x + threadIdx.x) >> 6;  // one wave per token
  const float* xr = x + (size_t)t * DDIM;
  float acc[NEXP];
#pragma unroll
  for (int e = 0; e < NEXP; ++e) acc[e] = 0.f;
#pragma unroll
  for (int it = 0; it < DDIM / 256; ++it) {
    const int d = (it * 64 + lane) * 4;
    const float4 xv = *(const float4*)(xr + d);
    u16x4 xb; xb[0]=f2bf(xv.x); xb[1]=f2bf(xv.y); xb[2]=f2bf(xv.z); xb[3]=f2bf(xv.w);
    *(u16x4*)(xbf + (size_t)t * DDIM + d) = xb;
#pragma unroll
    for (int e = 0; e < NEXP; ++e) {
      const float4 gv = *(const float4*)(gw + (size_t)e * DDIM + d);
      acc[e] += xv.x*gv.x + xv.y*gv.y + xv.z*gv.z + xv.w*gv.w;
    }
  }
#pragma unroll
  for (int e = 0; e < NEXP; ++e) {
    float v = acc[e];
#pragma unroll
    for (int off = 32; off > 0; off >>= 1) v += __shfl_xor(v, off);
    acc[e] = v;
  }
  if (lane == 0) {
    int i0 = 0; float v0 = acc[0];
#pragma unroll
    for (int e = 1; e < NEXP; ++e) if (acc[e] > v0) { v0 = acc[e]; i0 = e; }
    int i1 = -1; float v1 = -3.4e38f;
#pragma unroll
    for (int e = 0; e < NEXP; ++e) { if (e == i0) continue; if (acc[e] > v1) { v1 = acc[e]; i1 = e; } }
    const float e1 = __expf(v1 - v0);
    const float w0 = 1.f / (1.f + e1);
    const float w1 = e1 / (1.f + e1);
    const int p0 = atomicAdd(&cnt[i0], 1);
    slots[i0 * TTOK + p0] = t * 2;     wts[i0 * TTOK + p0] = w0;
    const int p1 = atomicAdd(&cnt[i1], 1);
    slots[i1 * TTOK + p1] = t * 2 + 1; wts[i1 * TTOK + p1] = w1;
  }
}

// ---------------- plan: 256-row tiles, padded prefix offsets ----------------
__global__ void plan_kernel(const int* __restrict__ cnt,
                            int* __restrict__ tilemap, int* __restrict__ ntiles,
                            int* __restrict__ po)
{
  if (threadIdx.x == 0 && blockIdx.x == 0) {
    int n = 0, off = 0;
#pragma unroll
    for (int e = 0; e < NEXP; ++e) {
      po[e] = off;
      const int nt = (cnt[e] + 255) >> 8;
      for (int m = 0; m < nt; ++m) tilemap[n++] = (e << 8) | m;
      off += nt << 8;
    }
    ntiles[0] = n;   // <= 24
  }
}

// chunk swizzle: 16B chunk c of row r stored at chunk c ^ (r & 7)

// ---- gate+up grouped GEMM: 256M x (128g||128u), BK=64, 8-wave 8-phase ----
__global__ __launch_bounds__(512, 2) void gateup_kernel(
    const unsigned short* __restrict__ xbf,
    const float* __restrict__ wg, const float* __restrict__ wu,
    const int* __restrict__ cnt, const int* __restrict__ slots,
    const int* __restrict__ po,
    const int* __restrict__ tilemap, const int* __restrict__ ntiles,
    unsigned short* __restrict__ h)
{
  // grid 1056 = 24 slots x 44 I-panels; XCD swizzle (q=132), tile fastest
  const int flat = (blockIdx.x & 7) * 132 + (blockIdx.x >> 3);
  const int ti = flat % 24;
  if (ti >= ntiles[0]) return;
  const int em = tilemap[ti];
  const int e = em >> 8;
  const int mt = em & 255;
  const int n0 = (flat / 24) * 128;
  const int count = cnt[e];
  const int m0 = mt * 256;
  const int abase = po[e] + m0;

  __shared__ unsigned short SA[2][256][64];   // 64 KB (epilogue: u-exchange wc=2)
  __shared__ unsigned short SB[2][256][64];   // 64 KB (epilogue: u-exchange wc=3)
  __shared__ int rtok[256];

  const int tid = threadIdx.x;
  const int lane = tid & 63;
  const int wid = tid >> 6;

  if (tid < 256) {
    const int idx = m0 + tid;
    rtok[tid] = (idx < count) ? (slots[e * TTOK + idx] >> 1) : (slots[e * TTOK + m0] >> 1);
  }
  __syncthreads();

  // A: gathered rows, source chunk pre-swizzled (linear gload_lds dest)
  const int aswz = ((lane & 7) ^ ((lane >> 3) & 7)) * 8;
  const unsigned short* ap00 = xbf + (size_t)rtok[      wid * 16     + (lane >> 3)] * DDIM + aswz;
  const unsigned short* ap01 = xbf + (size_t)rtok[      wid * 16 + 8 + (lane >> 3)] * DDIM + aswz;
  const unsigned short* ap10 = xbf + (size_t)rtok[128 + wid * 16     + (lane >> 3)] * DDIM + aswz;
  const unsigned short* ap11 = xbf + (size_t)rtok[128 + wid * 16 + 8 + (lane >> 3)] * DDIM + aswz;

  // B: 16 fp32/thread per half (half0 = wg rows, half1 = wu rows)
  const int brow = tid >> 2;
  const int bcb = (tid & 3) * 2;
  const int bswz = brow & 7;
  const size_t wo = (size_t)e * IDIM * DDIM + (size_t)(n0 + brow) * DDIM + bcb * 8;
  const float* gsrc = wg + wo;
  const float* usrc = wu + wo;

  const int wr = wid >> 2;     // 0..1 (128-row half)
  const int wc = wid & 3;      // 0..3 (64-col group of the 256 B-rows)
  const int fr = lane & 15;
  const int kc = lane >> 4;
  const int rsw = fr & 7;

  f32x4 acc[8][4] = {};
  bf16x8 bfr[4];
  float4 Bst[8];

  // prologue: A(0)->buf0; B(0)->regs->buf0; B(1)->regs; publish
  gload16(ap00, &SA[0][wid * 16][0]);
  gload16(ap01, &SA[0][wid * 16 + 8][0]);
  gload16(ap10, &SA[0][128 + wid * 16][0]);
  gload16(ap11, &SA[0][128 + wid * 16 + 8][0]);
  Bst[0] = *(const float4*)(gsrc);      Bst[1] = *(const float4*)(gsrc + 4);
  Bst[2] = *(const float4*)(gsrc + 8);  Bst[3] = *(const float4*)(gsrc + 12);
  Bst[4] = *(const float4*)(usrc);      Bst[5] = *(const float4*)(usrc + 4);
  Bst[6] = *(const float4*)(usrc + 8);  Bst[7] = *(const float4*)(usrc + 12);
  WRITE_B(0, 0, Bst[0], Bst[1], Bst[2], Bst[3]);
  WRITE_B(0, 1, Bst[4], Bst[5], Bst[6], Bst[7]);
  Bst[0] = *(const float4*)(gsrc + 64);      Bst[1] = *(const float4*)(gsrc + 68);
  Bst[2] = *(const float4*)(gsrc + 72);      Bst[3] = *(const float4*)(gsrc + 76);
  Bst[4] = *(const float4*)(usrc + 64);      Bst[5] = *(const float4*)(usrc + 68);
  Bst[6] = *(const float4*)(usrc + 72);      Bst[7] = *(const float4*)(usrc + 76);
  asm volatile("s_waitcnt lgkmcnt(0)" ::: "memory");
  __builtin_amdgcn_s_barrier();

#pragma unroll 1
  for (int it = 0; it < 16; ++it) {
    const int t = 2 * it;
    const int k1 = (t + 1) * 64;
    const int k2 = ((t + 2 < 32) ? t + 2 : 31) * 64;
    const int k3 = ((t + 3 < 32) ? t + 3 : 31) * 64;

    PHASE(0, 0, 0, 0,
      gload16(ap00 + k1, &SA[1][wid * 16][0]);
      gload16(ap01 + k1, &SA[1][wid * 16 + 8][0]);
      WRITE_B(1, 0, Bst[0], Bst[1], Bst[2], Bst[3]));
    PHASE(0, 0, 1, 0,
      gload16(ap10 + k1, &SA[1][128 + wid * 16][0]);
      gload16(ap11 + k1, &SA[1][128 + wid * 16 + 8][0]);
      WRITE_B(1, 1, Bst[4], Bst[5], Bst[6], Bst[7]));
    PHASE(0, 1, 0, 0,
      Bst[0] = *(const float4*)(gsrc + k2);
      Bst[1] = *(const float4*)(gsrc + k2 + 4);
      Bst[2] = *(const float4*)(gsrc + k2 + 8);
      Bst[3] = *(const float4*)(gsrc + k2 + 12));
    PHASE(0, 1, 1, 1,
      Bst[4] = *(const float4*)(usrc + k2);
      Bst[5] = *(const float4*)(usrc + k2 + 4);
      Bst[6] = *(const float4*)(usrc + k2 + 8);
      Bst[7] = *(const float4*)(usrc + k2 + 12));
    PHASE(1, 0, 0, 0,
      gload16(ap00 + k2, &SA[0][wid * 16][0]);
      gload16(ap01 + k2, &SA[0][wid * 16 + 8][0]);
      WRITE_B(0, 0, Bst[0], Bst[1], Bst[2], Bst[3]));
    PHASE(1, 0, 1, 0,
      gload16(ap10 + k2, &SA[0][128 + wid * 16][0]);
      gload16(ap11 + k2, &SA[0][128 + wid * 16 + 8][0]);
      WRITE_B(0, 1, Bst[4], Bst[5], Bst[6], Bst[7]));
    PHASE(1, 1, 0, 0,
      Bst[0] = *(const float4*)(gsrc + k3);
      Bst[1] = *(const float4*)(gsrc + k3 + 4);
      Bst[2] = *(const float4*)(gsrc + k3 + 8);
      Bst[3] = *(const float4*)(gsrc + k3 + 12));
    PHASE(1, 1, 1, 1,
      Bst[4] = *(const float4*)(usrc + k3);
      Bst[5] = *(const float4*)(usrc + k3 + 4);
      Bst[6] = *(const float4*)(usrc + k3 + 8);
      Bst[7] = *(const float4*)(usrc + k3 + 12));
  }

  // epilogue: u-waves (wc>=2) export via LDS overlay, g-waves fuse SiLU
  __syncthreads();
  if (wc >= 2) {
    float* uex = (wc == 2) ? (float*)&SA[0][0][0] : (float*)&SB[0][0][0];
#pragma unroll
    for (int mf = 0; mf < 8; ++mf)
#pragma unroll
      for (int nf = 0; nf < 4; ++nf)
#pragma unroll
        for (int j = 0; j < 4; ++j) {
          const int r = wr * 128 + mf * 16 + (lane >> 4) * 4 + j;
          uex[r * 64 + nf * 16 + fr] = acc[mf][nf][j];
        }
  }
  __syncthreads();
  if (wc < 2) {
    const float* uex = (wc == 0) ? (const float*)&SA[0][0][0] : (const float*)&SB[0][0][0];
#pragma unroll
    for (int mf = 0; mf < 8; ++mf)
#pragma unroll
      for (int nf = 0; nf < 4; ++nf)
#pragma unroll
        for (int j = 0; j < 4; ++j) {
          const int r = wr * 128 + mf * 16 + (lane >> 4) * 4 + j;
          if (m0 + r < count) {
            const float g = acc[mf][nf][j];
            const float u = uex[r * 64 + nf * 16 + fr];
            const float hv = g / (1.f + __expf(-g)) * u;
            h[(size_t)(abase + r) * IDIM + n0 + wc * 64 + nf * 16 + fr] = f2bf(hv);
          }
        }
  }
}

// ---- down grouped GEMM: 256M x 256N, K-split x4, 8-wave 8-phase, scatter-add ----
__global__ __launch_bounds__(512, 2) void down_kernel(
    const unsigned short* __restrict__ hb,
    const float* __restrict__ wd,
    const int* __restrict__ cnt, const int* __restrict__ slots,
    const float* __restrict__ wts, const int* __restrict__ po,
    const int* __restrict__ tilemap, const int* __restrict__ ntiles,
    float* __restrict__ out)
{
  // grid 768 = 24 slots x 8 D-panels x 4 k-splits; XCD swizzle (q=96)
  const int flat = (blockIdx.x & 7) * 96 + (blockIdx.x >> 3);
  const int ti = flat % 24;
  if (ti >= ntiles[0]) return;
  const int em = tilemap[ti];
  const int e = em >> 8;
  const int mt = em & 255;
  const int rest = flat / 24;            // 0..31
  const int n0 = (rest & 7) * 256;
  const int kbase = (rest >> 3) * 1408;  // IDIM/4
  const int count = cnt[e];
  const int m0 = mt * 256;
  const int abase = po[e] + m0;

  __shared__ unsigned short SA[2][256][64];
  __shared__ unsigned short SB[2][256][64];
  __shared__ int rtok[256];
  __shared__ float rw[256];

  const int tid = threadIdx.x;
  const int lane = tid & 63;
  const int wid = tid >> 6;

  if (tid < 256) {
    const int idx = m0 + tid;
    rtok[tid] = (idx < count) ? (slots[e * TTOK + idx] >> 1) : 0;
    rw[tid] = (idx < count) ? wts[e * TTOK + idx] : 0.f;
  }

  const int aswz = ((lane & 7) ^ ((lane >> 3) & 7)) * 8;
  const unsigned short* ap00 = hb + (size_t)(abase +       wid * 16     + (lane >> 3)) * IDIM + kbase + aswz;
  const unsigned short* ap01 = hb + (size_t)(abase +       wid * 16 + 8 + (lane >> 3)) * IDIM + kbase + aswz;
  const unsigned short* ap10 = hb + (size_t)(abase + 128 + wid * 16     + (lane >> 3)) * IDIM + kbase + aswz;
  const unsigned short* ap11 = hb + (size_t)(abase + 128 + wid * 16 + 8 + (lane >> 3)) * IDIM + kbase + aswz;

  const int brow = tid >> 2;
  const int bcb = (tid & 3) * 2;
  const int bswz = brow & 7;
  const float* bsrc0 = wd + (size_t)e * DDIM * IDIM + (size_t)(n0 + brow) * IDIM + kbase + bcb * 8;
  const float* bsrc1 = wd + (size_t)e * DDIM * IDIM + (size_t)(n0 + 128 + brow) * IDIM + kbase + bcb * 8;

  const int wr = wid >> 2;
  const int wc = wid & 3;
  const int fr = lane & 15;
  const int kc = lane >> 4;
  const int rsw = fr & 7;

  f32x4 acc[8][4] = {};
  bf16x8 bfr[4];
  float4 Bst[8];

  // prologue
  gload16(ap00, &SA[0][wid * 16][0]);
  gload16(ap01, &SA[0][wid * 16 + 8][0]);
  gload16(ap10, &SA[0][128 + wid * 16][0]);
  gload16(ap11, &SA[0][128 + wid * 16 + 8][0]);
  Bst[0] = *(const float4*)(bsrc0);      Bst[1] = *(const float4*)(bsrc0 + 4);
  Bst[2] = *(const float4*)(bsrc0 + 8);  Bst[3] = *(const float4*)(bsrc0 + 12);
  Bst[4] = *(const float4*)(bsrc1);      Bst[5] = *(const float4*)(bsrc1 + 4);
  Bst[6] = *(const float4*)(bsrc1 + 8);  Bst[7] = *(const float4*)(bsrc1 + 12);
  WRITE_B(0, 0, Bst[0], Bst[1], Bst[2], Bst[3]);
  WRITE_B(0, 1, Bst[4], Bst[5], Bst[6], Bst[7]);
  Bst[0] = *(const float4*)(bsrc0 + 64);      Bst[1] = *(const float4*)(bsrc0 + 68);
  Bst[2] = *(const float4*)(bsrc0 + 72);      Bst[3] = *(const float4*)(bsrc0 + 76);
  Bst[4] = *(const float4*)(bsrc1 + 64);      Bst[5] = *(const float4*)(bsrc1 + 68);
  Bst[6] = *(const float4*)(bsrc1 + 72);      Bst[7] = *(const float4*)(bsrc1 + 76);
  asm volatile("s_waitcnt lgkmcnt(0)" ::: "memory");
  __builtin_amdgcn_s_barrier();

#pragma unroll 1
  for (int it = 0; it < 11; ++it) {
    const int t = 2 * it;
    const int k1 = (t + 1) * 64;
    const int k2 = ((t + 2 < 22) ? t + 2 : 21) * 64;
    const int k3 = ((t + 3 < 22) ? t + 3 : 21) * 64;

    PHASE(0, 0, 0, 0,
      gload16(ap00 + k1, &SA[1][wid * 16][0]);
      gload16(ap01 + k1, &SA[1][wid * 16 + 8][0]);
      WRITE_B(1, 0, Bst[0], Bst[1], Bst[2], Bst[3]));
    PHASE(0, 0, 1, 0,
      gload16(ap10 + k1, &SA[1][128 + wid * 16][0]);
      gload16(ap11 + k1, &SA[1][128 + wid * 16 + 8][0]);
      WRITE_B(1, 1, Bst[4], Bst[5], Bst[6], Bst[7]));
    PHASE(0, 1, 0, 0,
      Bst[0] = *(const float4*)(bsrc0 + k2);
      Bst[1] = *(const float4*)(bsrc0 + k2 + 4);
      Bst[2] = *(const float4*)(bsrc0 + k2 + 8);
      Bst[3] = *(const float4*)(bsrc0 + k2 + 12));
    PHASE(0, 1, 1, 1,
      Bst[4] = *(const float4*)(bsrc1 + k2);
      Bst[5] = *(const float4*)(bsrc1 + k2 + 4);
      Bst[6] = *(const float4*)(bsrc1 + k2 + 8);
      Bst[7] = *(const float4*)(bsrc1 + k2 + 12));
    PHASE(1, 0, 0, 0,
      gload16(ap00 + k2, &SA[0][wid * 16][0]);
      gload16(ap01 + k2, &SA[0][wid * 16 + 8][0]);
      WRITE_B(0, 0, Bst[0], Bst[1], Bst[2], Bst[3]));
    PHASE(1, 0, 1, 0,
      gload16(ap10 + k2, &SA[0][128 + wid * 16][0]);
      gload16(ap11 + k2, &SA[0][128 + wid * 16 + 8][0]);
      WRITE_B(0, 1, Bst[4], Bst[5], Bst[6], Bst[7]));
    PHASE(1, 1, 0, 0,
      Bst[0] = *(const float4*)(bsrc0 + k3);
      Bst[1] = *(const float4*)(bsrc0 + k3 + 4);
      Bst[2] = *(const float4*)(bsrc0 + k3 + 8);
      Bst[3] = *(const float4*)(bsrc0 + k3 + 12));
    PHASE(1, 1, 1, 1,
      Bst[4] = *(const float4*)(bsrc1 + k3);
      Bst[5] = *(const float4*)(bsrc1 + k3 + 4);
      Bst[6] = *(const float4*)(bsrc1 + k3 + 8);
      Bst[7] = *(const float4*)(bsrc1 + k3 + 12));
  }

  // epilogue: weighted scatter-add per token
#pragma unroll
  for (int mf = 0; mf < 8; ++mf)
#pragma unroll
    for (int j = 0; j < 4; ++j) {
      const int r = wr * 128 + mf * 16 + (lane >> 4) * 4 + j;
      if (m0 + r < count) {
        const int t2 = rtok[r];
        const float w = rw[r];
#pragma unroll
        for (int nf = 0; nf < 4; ++nf)
          atomicAdd(out + (size_t)t2 * DDIM + n0 + wc * 64 + nf * 16 + fr,
                    acc[mf][nf][j] * w);
      }
    }
}

extern "C" void kernel_launch(void* const* d_in, const int* in_sizes, int n_in,
                              void* d_out, int out_size, void* d_ws, size_t ws_size,
                              hipStream_t stream) {
  const float* x  = (const float*)d_in[0];
  const float* gw = (const float*)d_in[1];
  const float* wg = (const float*)d_in[2];
  const float* wu = (const float*)d_in[3];
  const float* wd = (const float*)d_in[4];
  float* out = (float*)d_out;

  char* ws = (char*)d_ws;
  unsigned short* xbf = (unsigned short*)ws;                 // 8,388,608 B
  unsigned short* h   = (unsigned short*)(ws + 8388608);     // 6144*5632*2 = 69,206,016 B
  int*   slots = (int*)(ws + 77594624);                      // 65,536 B
  float* wts   = (float*)(ws + 77660160);                    // 65,536 B
  int*   cnt   = (int*)(ws + 77725696);                      // 32 B
  int*   tmap  = (int*)(ws + 77725728);                      // 128 B
  int*   ntl   = (int*)(ws + 77725856);                      // 4 B
  int*   po    = (int*)(ws + 77725860);                      // 32 B

  hipMemsetAsync(cnt, 0, NEXP * sizeof(int), stream);
  hipMemsetAsync(d_out, 0, (size_t)TTOK * DDIM * sizeof(float), stream);

  router_kernel<<<TTOK / 4, 256, 0, stream>>>(x, gw, xbf, cnt, slots, wts);
  plan_kernel<<<1, 64, 0, stream>>>(cnt, tmap, ntl, po);
  gateup_kernel<<<1056, 512, 0, stream>>>(xbf, wg, wu, cnt, slots, po, tmap, ntl, h);
  down_kernel<<<768, 512, 0, stream>>>(h, wd, cnt, slots, wts, po, tmap, ntl, out);
}